// Round 11
// baseline (588.439 us; speedup 1.0000x reference)
//
#include <hip/hip_runtime.h>
#include <math.h>

// OCRHead decomposition (R9: ocr occupancy fix — VGPR 68>64 cliff halved waves;
// now 2 ch/wave (acc 38 regs) + 2 px/lane float2 ILP. softmax widened to 1024 thr):
//   attn  = softmax(ctx)
//   ocr   = Feature @ attn^T (fp32, fused f16x2 pack of feature -> fpk)
//   ocr2  = W1 @ ocr ; w2a = w2_left . ocr2 ; bcon = w2_left . b1
//   rel   = ocr^T @ Feature (fdot2)
//   attn2 = softmax(rel)
//   outa  = b2 + masked bcon + conv3x3(attn2, w2a)   [plain store]
//   out  += conv3x3(feature, w2_right)               [fdot2 from LDS-staged taps, atomic]

typedef _Float16 h2 __attribute__((ext_vector_type(2)));
typedef _Float16 h4 __attribute__((ext_vector_type(4)));

#define BB 4
#define KK 19
#define CC 512
#define C2 (CC/2)
#define HH 128
#define WW 128
#define HWHW (HH*WW)

// ---------------- softmax over rows of length HW (1024 thr, 16 waves) ----------------
__global__ __launch_bounds__(1024) void softmax_rows(const float* __restrict__ in,
                                                     float* __restrict__ out) {
    int row = blockIdx.x;
    const float* r = in + (size_t)row * HWHW;
    float* o = out + (size_t)row * HWHW;
    int t = threadIdx.x;
    float v[16];
    float m = -1e30f;
#pragma unroll
    for (int i = 0; i < 16; ++i) { v[i] = r[t + i * 1024]; m = fmaxf(m, v[i]); }
    for (int off = 32; off; off >>= 1) m = fmaxf(m, __shfl_xor(m, off));
    __shared__ float sm[16], ss[16];
    int wave = t >> 6;
    if ((t & 63) == 0) sm[wave] = m;
    __syncthreads();
#pragma unroll
    for (int i = 0; i < 16; ++i) m = fmaxf(m, sm[i]);
    float s = 0.f;
#pragma unroll
    for (int i = 0; i < 16; ++i) { v[i] = __expf(v[i] - m); s += v[i]; }
    for (int off = 32; off; off >>= 1) s += __shfl_xor(s, off);
    if ((t & 63) == 0) ss[wave] = s;
    __syncthreads();
    s = 0.f;
#pragma unroll
    for (int i = 0; i < 16; ++i) s += ss[i];
    float inv = 1.f / s;
#pragma unroll
    for (int i = 0; i < 16; ++i) o[t + i * 1024] = v[i] * inv;
}

// ---------------- ocr[b,c,k] = sum_n attn[b,k,n]*feature[b,c,n]; also packs fpk ----------------
// R9: 2 channels/wave, 2 px/lane (float2). grid (64 ctiles, B, 8), block 256.
#define NSPLIT 8
__global__ __launch_bounds__(256) void ocr_kernel(const float* __restrict__ feature,
                                                  const float* __restrict__ attn,
                                                  float* __restrict__ ocr,
                                                  h2* __restrict__ fpk) {
    int ctile = blockIdx.x, b = blockIdx.y, ns = blockIdx.z;
    int t = threadIdx.x, wave = t >> 6, lane = t & 63;
    int c0 = ctile * 8 + wave * 2;  // even
    const float* fbase = feature + (size_t)b * CC * HWHW;
    const float* abase = attn + (size_t)b * KK * HWHW;
    h2* fpb = fpk + (size_t)b * C2 * HWHW;
    float acc[2][KK];
#pragma unroll
    for (int j = 0; j < 2; ++j)
#pragma unroll
        for (int k = 0; k < KK; ++k) acc[j][k] = 0.f;
    int nstart = ns * (HWHW / NSPLIT);
    for (int it = 0; it < (HWHW / NSPLIT) / 128; ++it) {  // 16 iters
        int n = nstart + it * 128 + lane * 2;
        float2 f0 = *(const float2*)&fbase[(size_t)c0 * HWHW + n];
        float2 f1 = *(const float2*)&fbase[(size_t)(c0 + 1) * HWHW + n];
        // pack channel-pair (c0,c0+1) for px n, n+1 -> one 8B store
        h4 pp;
        pp[0] = (_Float16)f0.x; pp[1] = (_Float16)f1.x;
        pp[2] = (_Float16)f0.y; pp[3] = (_Float16)f1.y;
        *(h4*)&fpb[(size_t)(c0 >> 1) * HWHW + n] = pp;
#pragma unroll
        for (int k = 0; k < KK; ++k) {
            float2 a = *(const float2*)&abase[(size_t)k * HWHW + n];
            acc[0][k] += f0.x * a.x + f0.y * a.y;
            acc[1][k] += f1.x * a.x + f1.y * a.y;
        }
    }
#pragma unroll
    for (int j = 0; j < 2; ++j)
#pragma unroll
        for (int k = 0; k < KK; ++k) {
            float x = acc[j][k];
            for (int off = 32; off; off >>= 1) x += __shfl_xor(x, off);
            if (lane == 0) atomicAdd(&ocr[((size_t)b * CC + (c0 + j)) * KK + k], x);
        }
}

// ---------------- ocr2[b,co,k] = sum_ci w1[co,ci]*ocr[b,ci,k] ----------------
__global__ __launch_bounds__(64) void ocr2_kernel(const float* __restrict__ w1,
                                                  const float* __restrict__ ocr,
                                                  float* __restrict__ ocr2) {
    int co = blockIdx.x, b = blockIdx.y, lane = threadIdx.x;
    float acc[KK];
#pragma unroll
    for (int k = 0; k < KK; ++k) acc[k] = 0.f;
    const float* wrow = w1 + (size_t)co * CC;
    const float* ob = ocr + (size_t)b * CC * KK;
    for (int ci = lane; ci < CC; ci += 64) {
        float w = wrow[ci];
#pragma unroll
        for (int k = 0; k < KK; ++k) acc[k] += w * ob[ci * KK + k];
    }
#pragma unroll
    for (int k = 0; k < KK; ++k) {
        float x = acc[k];
        for (int off = 32; off; off >>= 1) x += __shfl_xor(x, off);
        if (lane == 0) ocr2[((size_t)b * CC + co) * KK + k] = x;
    }
}

// ---------------- pack right-half conv weights: wpk[c2][ko*9+tap] ----------------
__global__ __launch_bounds__(256) void wpk_kernel(const float* __restrict__ w2,
                                                  h2* __restrict__ wpk) {
    int idx = blockIdx.x * 256 + threadIdx.x;
    if (idx >= C2 * 171) return;
    int c2 = idx / 171, j = idx % 171;
    int ko = j / 9, tap = j % 9;
    h2 p;
    p[0] = (_Float16)w2[((size_t)ko * (2 * CC) + CC + 2 * c2) * 9 + tap];
    p[1] = (_Float16)w2[((size_t)ko * (2 * CC) + CC + 2 * c2 + 1) * 9 + tap];
    wpk[idx] = p;
}

// ---------------- pack ocr channel-pairs: opk[b][c2][k] ----------------
__global__ __launch_bounds__(256) void opk_kernel(const float* __restrict__ ocr,
                                                  h2* __restrict__ opk) {
    int b = blockIdx.x, c2 = threadIdx.x;
    const float* ob = ocr + (size_t)b * CC * KK;
    h2* op = opk + (size_t)b * C2 * KK;
    for (int k = 0; k < KK; ++k) {
        h2 p;
        p[0] = (_Float16)ob[(2 * c2) * KK + k];
        p[1] = (_Float16)ob[(2 * c2 + 1) * KK + k];
        op[c2 * KK + k] = p;
    }
}

// ---------------- w2a[b,ko,k,tap] = sum_c w2[ko,c,tap]*ocr2[b,c,k]; bcon ----------------
__global__ __launch_bounds__(64) void w2a_kernel(const float* __restrict__ w2,
                                                 const float* __restrict__ ocr2,
                                                 const float* __restrict__ b1,
                                                 float* __restrict__ w2a,
                                                 float* __restrict__ bcon) {
    int ko = blockIdx.x, dydx = blockIdx.y, b = blockIdx.z, lane = threadIdx.x;
    float acc[KK];
#pragma unroll
    for (int k = 0; k < KK; ++k) acc[k] = 0.f;
    float accb = 0.f;
    for (int c = lane; c < CC; c += 64) {
        float wv = w2[((size_t)ko * (2 * CC) + c) * 9 + dydx];
#pragma unroll
        for (int k = 0; k < KK; ++k) acc[k] += wv * ocr2[((size_t)b * CC + c) * KK + k];
        accb += wv * b1[c];
    }
#pragma unroll
    for (int k = 0; k < KK; ++k) {
        float x = acc[k];
        for (int off = 32; off; off >>= 1) x += __shfl_xor(x, off);
        if (lane == 0) w2a[(((size_t)b * KK + ko) * KK + k) * 9 + dydx] = x;
    }
    for (int off = 32; off; off >>= 1) accb += __shfl_xor(accb, off);
    if (lane == 0 && b == 0) bcon[ko * 9 + dydx] = accb;
}

// ---------------- rel (R5 form, measured-good): 1 px/lane, NSREL 4 ----------------
#define NSREL 4
__global__ __launch_bounds__(256) void rel_kernel(const h2* __restrict__ fpk,
                                                  const h2* __restrict__ opk,
                                                  float* __restrict__ rel) {
    int b = blockIdx.y, ns = blockIdx.z;
    int n = blockIdx.x * 256 + threadIdx.x;
    int cb = ns * (C2 / NSREL);
    const h2* fb = fpk + ((size_t)b * C2 + cb) * HWHW + n;
    const h2* ob = opk + ((size_t)b * C2 + cb) * KK;  // wave-uniform
    float acc[KK];
#pragma unroll
    for (int k = 0; k < KK; ++k) acc[k] = 0.f;
    for (int c2 = 0; c2 < C2 / NSREL; ++c2) {
        h2 f = fb[(size_t)c2 * HWHW];
#pragma unroll
        for (int k = 0; k < KK; ++k)
            acc[k] = __builtin_amdgcn_fdot2(f, ob[c2 * KK + k], acc[k], false);
    }
#pragma unroll
    for (int k = 0; k < KK; ++k)
        atomicAdd(&rel[((size_t)b * KK + k) * HWHW + n], acc[k]);
}

// ---------------- outa: out = b2 + masked bcon + conv3x3(attn2, w2a); plain store ----------------
__global__ __launch_bounds__(256) void outa_kernel(const float* __restrict__ attn2,
                                                   const float* __restrict__ w2a,
                                                   const float* __restrict__ bcon,
                                                   const float* __restrict__ b2,
                                                   float* __restrict__ out) {
    int b = blockIdx.y;
    int px = blockIdx.x * 256 + threadIdx.x;
    int y = px >> 7, x = px & 127;

    float m[9];
    int off[9];
#pragma unroll
    for (int dy = -1; dy <= 1; ++dy)
#pragma unroll
        for (int dx = -1; dx <= 1; ++dx) {
            int i = (dy + 1) * 3 + (dx + 1);
            int yy = y + dy, xx = x + dx;
            bool valid = (yy >= 0 && yy < HH && xx >= 0 && xx < WW);
            m[i] = valid ? 1.f : 0.f;
            int yc = min(max(yy, 0), HH - 1), xc = min(max(xx, 0), WW - 1);
            off[i] = yc * WW + xc;
        }

    float acc[KK];
#pragma unroll
    for (int ko = 0; ko < KK; ++ko) acc[ko] = b2[ko];
#pragma unroll
    for (int i = 0; i < 9; ++i)
#pragma unroll
        for (int ko = 0; ko < KK; ++ko) acc[ko] += m[i] * bcon[ko * 9 + i];

    const float* a2b = attn2 + (size_t)b * KK * HWHW;
    const float* wab = w2a + (size_t)b * KK * KK * 9;
    float tap[2][9];
#pragma unroll
    for (int i = 0; i < 9; ++i) tap[0][i] = m[i] * a2b[off[i]];  // k=0
#pragma unroll 2
    for (int k = 0; k < KK; ++k) {
        if (k < KK - 1) {
#pragma unroll
            for (int i = 0; i < 9; ++i)
                tap[(k + 1) & 1][i] = m[i] * a2b[(size_t)(k + 1) * HWHW + off[i]];
        }
#pragma unroll
        for (int ko = 0; ko < KK; ++ko)
#pragma unroll
            for (int i = 0; i < 9; ++i)
                acc[ko] += wab[(ko * KK + k) * 9 + i] * tap[k & 1][i];
    }

    size_t obase = ((size_t)b * KK) * HWHW + (size_t)y * WW + x;
#pragma unroll
    for (int ko = 0; ko < KK; ++ko) out[obase + (size_t)ko * HWHW] = acc[ko];
}

// ---------------- out += conv3x3(feature, w2_right); LDS tap staging ----------------
#define NSOUT 8
#define SUBC 8
__global__ __launch_bounds__(256) void out_kernel(const h2* __restrict__ fpk,
                                                  const h2* __restrict__ wpk,
                                                  float* __restrict__ out) {
    __shared__ h2 st[SUBC * 4 * 130];  // 16640 B
    int b = blockIdx.y, ns = blockIdx.z;
    int t = threadIdx.x;
    int w = t >> 7;   // output row within block (0/1)
    int x = t & 127;
    int y0 = blockIdx.x * 2;

    h2 hz; hz[0] = (_Float16)0.f; hz[1] = (_Float16)0.f;

    // zero the two halo columns once (stage loop never writes x-index 0 or 129)
    if (t < SUBC * 4 * 2) {
        int c2r = t >> 1;
        int side = t & 1;
        st[c2r * 130 + side * 129] = hz;
    }

    int cb = ns * (C2 / NSOUT);  // 32 c2 per block
    const h2* fbase = fpk + ((size_t)b * C2 + cb) * HWHW;

    float acc[KK];
#pragma unroll
    for (int ko = 0; ko < KK; ++ko) acc[ko] = 0.f;

    for (int ch = 0; ch < (C2 / NSOUT) / SUBC; ++ch) {  // 4 chunks
        __syncthreads();  // prev compute done (also covers halo init on ch=0)
#pragma unroll
        for (int e = 0; e < (SUBC * 4 * 128) / 256; ++e) {  // 16 staging loads
            int idx = e * 256 + t;
            int c2s = idx >> 9;
            int rem = idx & 511;
            int r = rem >> 7;
            int xx = rem & 127;
            int yy = y0 - 1 + r;
            h2 v = hz;
            if (yy >= 0 && yy < HH)
                v = fbase[(size_t)(ch * SUBC + c2s) * HWHW + yy * WW + xx];
            st[(c2s * 4 + r) * 130 + xx + 1] = v;
        }
        __syncthreads();
        for (int c2s = 0; c2s < SUBC; ++c2s) {
            h2 tp[9];
#pragma unroll
            for (int dy = 0; dy < 3; ++dy)
#pragma unroll
                for (int dx = 0; dx < 3; ++dx)
                    tp[dy * 3 + dx] = st[(c2s * 4 + w + dy) * 130 + x + dx];
            const h2* wr = wpk + (size_t)(cb + ch * SUBC + c2s) * 171;  // uniform -> s_load
#pragma unroll
            for (int j = 0; j < 171; ++j)
                acc[j / 9] = __builtin_amdgcn_fdot2(wr[j], tp[j % 9], acc[j / 9], false);
        }
    }

    size_t obase = ((size_t)b * KK) * HWHW + (size_t)(y0 + w) * WW + x;
#pragma unroll
    for (int ko = 0; ko < KK; ++ko) atomicAdd(&out[obase + (size_t)ko * HWHW], acc[ko]);
}

extern "C" void kernel_launch(void* const* d_in, const int* in_sizes, int n_in,
                              void* d_out, int out_size, void* d_ws, size_t ws_size,
                              hipStream_t stream) {
    const float* ctx = (const float*)d_in[0];
    const float* feature = (const float*)d_in[1];
    const float* w1 = (const float*)d_in[2];
    const float* b1 = (const float*)d_in[3];
    const float* w2 = (const float*)d_in[4];
    const float* b2 = (const float*)d_in[5];
    float* out = (float*)d_out;

    // workspace layout
    float* ws = (float*)d_ws;
    float* attn = ws;                              // B*K*HW (reused as rel/attn2)
    float* ocr = attn + (size_t)BB * KK * HWHW;    // 38,912
    float* ocr2 = ocr + (size_t)BB * CC * KK;      // 38,912
    float* w2a = ocr2 + (size_t)BB * CC * KK;      // 12,996
    float* bcon = w2a + (size_t)BB * KK * KK * 9;  // 171
    h2* fpk = (h2*)(bcon + KK * 9 + 1);            // B*C2*HW h2 = 67.1 MB
    h2* opk = fpk + (size_t)BB * C2 * HWHW;        // B*C2*K
    h2* wpk = opk + (size_t)BB * C2 * KK;          // C2*171

    hipMemsetAsync(ocr, 0, (size_t)BB * CC * KK * sizeof(float), stream);

    softmax_rows<<<BB * KK, 1024, 0, stream>>>(ctx, attn);
    ocr_kernel<<<dim3(CC / 8, BB, NSPLIT), 256, 0, stream>>>(feature, attn, ocr, fpk);
    ocr2_kernel<<<dim3(CC, BB), 64, 0, stream>>>(w1, ocr, ocr2);
    wpk_kernel<<<(C2 * 171 + 255) / 256, 256, 0, stream>>>(w2, wpk);
    w2a_kernel<<<dim3(KK, 9, BB), 64, 0, stream>>>(w2, ocr2, b1, w2a, bcon);
    opk_kernel<<<BB, 256, 0, stream>>>(ocr, opk);
    // reuse attn buffer for rel accumulation
    hipMemsetAsync(attn, 0, (size_t)BB * KK * HWHW * sizeof(float), stream);
    rel_kernel<<<dim3(HWHW / 256, BB, NSREL), 256, 0, stream>>>(fpk, opk, attn);
    softmax_rows<<<BB * KK, 1024, 0, stream>>>(attn, attn);  // attn2 in place
    // outa writes out fully (bias + bcon + rank-19 conv), then out_kernel atomically adds
    outa_kernel<<<dim3(HWHW / 256, BB), 256, 0, stream>>>(attn, w2a, bcon, b2, out);
    out_kernel<<<dim3(HH / 2, BB, NSOUT), 256, 0, stream>>>(fpk, wpk, out);
}

// Round 13
// 536.869 us; speedup vs baseline: 1.0961x; 1.0961x over previous
//
#include <hip/hip_runtime.h>
#include <math.h>

// OCRHead decomposition (R11: ocr LDS-staged attn — kill the 19-load/iter chain;
// 4 ch/wave amortization + 2 px/lane, block-shared attn tile):
//   attn  = softmax(ctx)
//   ocr   = Feature @ attn^T (fp32, fused f16x2 pack of feature -> fpk)
//   ocr2  = W1 @ ocr ; w2a = w2_left . ocr2 ; bcon = w2_left . b1
//   rel   = ocr^T @ Feature (fdot2)
//   attn2 = softmax(rel)
//   outa  = b2 + masked bcon + conv3x3(attn2, w2a)   [plain store]
//   out  += conv3x3(feature, w2_right)               [fdot2 from LDS-staged taps, atomic]

typedef _Float16 h2 __attribute__((ext_vector_type(2)));
typedef _Float16 h4 __attribute__((ext_vector_type(4)));

#define BB 4
#define KK 19
#define CC 512
#define C2 (CC/2)
#define HH 128
#define WW 128
#define HWHW (HH*WW)

// ---------------- softmax over rows of length HW (1024 thr, 16 waves) ----------------
__global__ __launch_bounds__(1024) void softmax_rows(const float* __restrict__ in,
                                                     float* __restrict__ out) {
    int row = blockIdx.x;
    const float* r = in + (size_t)row * HWHW;
    float* o = out + (size_t)row * HWHW;
    int t = threadIdx.x;
    float v[16];
    float m = -1e30f;
#pragma unroll
    for (int i = 0; i < 16; ++i) { v[i] = r[t + i * 1024]; m = fmaxf(m, v[i]); }
    for (int off = 32; off; off >>= 1) m = fmaxf(m, __shfl_xor(m, off));
    __shared__ float sm[16], ss[16];
    int wave = t >> 6;
    if ((t & 63) == 0) sm[wave] = m;
    __syncthreads();
#pragma unroll
    for (int i = 0; i < 16; ++i) m = fmaxf(m, sm[i]);
    float s = 0.f;
#pragma unroll
    for (int i = 0; i < 16; ++i) { v[i] = __expf(v[i] - m); s += v[i]; }
    for (int off = 32; off; off >>= 1) s += __shfl_xor(s, off);
    if ((t & 63) == 0) ss[wave] = s;
    __syncthreads();
    s = 0.f;
#pragma unroll
    for (int i = 0; i < 16; ++i) s += ss[i];
    float inv = 1.f / s;
#pragma unroll
    for (int i = 0; i < 16; ++i) o[t + i * 1024] = v[i] * inv;
}

// ---------------- ocr[b,c,k] = sum_n attn[b,k,n]*feature[b,c,n]; also packs fpk ----------------
// R11: 4 ch/wave, 2 px/lane, attn tile (19x128 fp32, 9.7KB) staged in LDS per iter.
// grid (CC/16, B, 8), block 256 (4 waves).
#define NSPLIT 8
__global__ __launch_bounds__(256) void ocr_kernel(const float* __restrict__ feature,
                                                  const float* __restrict__ attn,
                                                  float* __restrict__ ocr,
                                                  h2* __restrict__ fpk) {
    __shared__ float sa[KK * 128];  // 9728 B
    int ctile = blockIdx.x, b = blockIdx.y, ns = blockIdx.z;
    int t = threadIdx.x, wave = t >> 6, lane = t & 63;
    int c0 = ctile * 16 + wave * 4;  // even
    const float* fbase = feature + (size_t)b * CC * HWHW;
    const float* abase = attn + (size_t)b * KK * HWHW;
    h2* fpb = fpk + (size_t)b * C2 * HWHW;
    float acc[4][KK];
#pragma unroll
    for (int j = 0; j < 4; ++j)
#pragma unroll
        for (int k = 0; k < KK; ++k) acc[j][k] = 0.f;
    int nstart = ns * (HWHW / NSPLIT);
    for (int it = 0; it < (HWHW / NSPLIT) / 128; ++it) {  // 16 iters
        int n0 = nstart + it * 128;
        __syncthreads();  // previous tile fully consumed
        // cooperative attn stage: 19 rows x 32 float4 = 608 float4 over 256 thr
#pragma unroll
        for (int r = 0; r < 3; ++r) {
            int idx = r * 256 + t;
            if (idx < KK * 32) {
                int row = idx >> 5, c4 = idx & 31;
                float4 v = *(const float4*)&abase[(size_t)row * HWHW + n0 + c4 * 4];
                *(float4*)&sa[row * 128 + c4 * 4] = v;
            }
        }
        __syncthreads();
        int n = n0 + lane * 2;
        float2 f[4];
#pragma unroll
        for (int j = 0; j < 4; ++j)
            f[j] = *(const float2*)&fbase[(size_t)(c0 + j) * HWHW + n];
        // pack channel-pairs (c0,c0+1) and (c0+2,c0+3) for px n,n+1 -> two 8B stores
        h4 p0, p1;
        p0[0] = (_Float16)f[0].x; p0[1] = (_Float16)f[1].x;
        p0[2] = (_Float16)f[0].y; p0[3] = (_Float16)f[1].y;
        p1[0] = (_Float16)f[2].x; p1[1] = (_Float16)f[3].x;
        p1[2] = (_Float16)f[2].y; p1[3] = (_Float16)f[3].y;
        *(h4*)&fpb[(size_t)(c0 >> 1) * HWHW + n] = p0;
        *(h4*)&fpb[(size_t)((c0 >> 1) + 1) * HWHW + n] = p1;
#pragma unroll
        for (int k = 0; k < KK; ++k) {
            float2 a = *(const float2*)&sa[k * 128 + lane * 2];
#pragma unroll
            for (int j = 0; j < 4; ++j)
                acc[j][k] += f[j].x * a.x + f[j].y * a.y;
        }
    }
#pragma unroll
    for (int j = 0; j < 4; ++j)
#pragma unroll
        for (int k = 0; k < KK; ++k) {
            float x = acc[j][k];
            for (int off = 32; off; off >>= 1) x += __shfl_xor(x, off);
            if (lane == 0) atomicAdd(&ocr[((size_t)b * CC + (c0 + j)) * KK + k], x);
        }
}

// ---------------- ocr2[b,co,k] = sum_ci w1[co,ci]*ocr[b,ci,k] ----------------
__global__ __launch_bounds__(64) void ocr2_kernel(const float* __restrict__ w1,
                                                  const float* __restrict__ ocr,
                                                  float* __restrict__ ocr2) {
    int co = blockIdx.x, b = blockIdx.y, lane = threadIdx.x;
    float acc[KK];
#pragma unroll
    for (int k = 0; k < KK; ++k) acc[k] = 0.f;
    const float* wrow = w1 + (size_t)co * CC;
    const float* ob = ocr + (size_t)b * CC * KK;
    for (int ci = lane; ci < CC; ci += 64) {
        float w = wrow[ci];
#pragma unroll
        for (int k = 0; k < KK; ++k) acc[k] += w * ob[ci * KK + k];
    }
#pragma unroll
    for (int k = 0; k < KK; ++k) {
        float x = acc[k];
        for (int off = 32; off; off >>= 1) x += __shfl_xor(x, off);
        if (lane == 0) ocr2[((size_t)b * CC + co) * KK + k] = x;
    }
}

// ---------------- pack right-half conv weights: wpk[c2][ko*9+tap] ----------------
__global__ __launch_bounds__(256) void wpk_kernel(const float* __restrict__ w2,
                                                  h2* __restrict__ wpk) {
    int idx = blockIdx.x * 256 + threadIdx.x;
    if (idx >= C2 * 171) return;
    int c2 = idx / 171, j = idx % 171;
    int ko = j / 9, tap = j % 9;
    h2 p;
    p[0] = (_Float16)w2[((size_t)ko * (2 * CC) + CC + 2 * c2) * 9 + tap];
    p[1] = (_Float16)w2[((size_t)ko * (2 * CC) + CC + 2 * c2 + 1) * 9 + tap];
    wpk[idx] = p;
}

// ---------------- pack ocr channel-pairs: opk[b][c2][k] ----------------
__global__ __launch_bounds__(256) void opk_kernel(const float* __restrict__ ocr,
                                                  h2* __restrict__ opk) {
    int b = blockIdx.x, c2 = threadIdx.x;
    const float* ob = ocr + (size_t)b * CC * KK;
    h2* op = opk + (size_t)b * C2 * KK;
    for (int k = 0; k < KK; ++k) {
        h2 p;
        p[0] = (_Float16)ob[(2 * c2) * KK + k];
        p[1] = (_Float16)ob[(2 * c2 + 1) * KK + k];
        op[c2 * KK + k] = p;
    }
}

// ---------------- w2a[b,ko,k,tap] = sum_c w2[ko,c,tap]*ocr2[b,c,k]; bcon ----------------
__global__ __launch_bounds__(64) void w2a_kernel(const float* __restrict__ w2,
                                                 const float* __restrict__ ocr2,
                                                 const float* __restrict__ b1,
                                                 float* __restrict__ w2a,
                                                 float* __restrict__ bcon) {
    int ko = blockIdx.x, dydx = blockIdx.y, b = blockIdx.z, lane = threadIdx.x;
    float acc[KK];
#pragma unroll
    for (int k = 0; k < KK; ++k) acc[k] = 0.f;
    float accb = 0.f;
    for (int c = lane; c < CC; c += 64) {
        float wv = w2[((size_t)ko * (2 * CC) + c) * 9 + dydx];
#pragma unroll
        for (int k = 0; k < KK; ++k) acc[k] += wv * ocr2[((size_t)b * CC + c) * KK + k];
        accb += wv * b1[c];
    }
#pragma unroll
    for (int k = 0; k < KK; ++k) {
        float x = acc[k];
        for (int off = 32; off; off >>= 1) x += __shfl_xor(x, off);
        if (lane == 0) w2a[(((size_t)b * KK + ko) * KK + k) * 9 + dydx] = x;
    }
    for (int off = 32; off; off >>= 1) accb += __shfl_xor(accb, off);
    if (lane == 0 && b == 0) bcon[ko * 9 + dydx] = accb;
}

// ---------------- rel (R5 form, measured-good): 1 px/lane, NSREL 4 ----------------
#define NSREL 4
__global__ __launch_bounds__(256) void rel_kernel(const h2* __restrict__ fpk,
                                                  const h2* __restrict__ opk,
                                                  float* __restrict__ rel) {
    int b = blockIdx.y, ns = blockIdx.z;
    int n = blockIdx.x * 256 + threadIdx.x;
    int cb = ns * (C2 / NSREL);
    const h2* fb = fpk + ((size_t)b * C2 + cb) * HWHW + n;
    const h2* ob = opk + ((size_t)b * C2 + cb) * KK;  // wave-uniform
    float acc[KK];
#pragma unroll
    for (int k = 0; k < KK; ++k) acc[k] = 0.f;
    for (int c2 = 0; c2 < C2 / NSREL; ++c2) {
        h2 f = fb[(size_t)c2 * HWHW];
#pragma unroll
        for (int k = 0; k < KK; ++k)
            acc[k] = __builtin_amdgcn_fdot2(f, ob[c2 * KK + k], acc[k], false);
    }
#pragma unroll
    for (int k = 0; k < KK; ++k)
        atomicAdd(&rel[((size_t)b * KK + k) * HWHW + n], acc[k]);
}

// ---------------- outa: out = b2 + masked bcon + conv3x3(attn2, w2a); plain store ----------------
__global__ __launch_bounds__(256) void outa_kernel(const float* __restrict__ attn2,
                                                   const float* __restrict__ w2a,
                                                   const float* __restrict__ bcon,
                                                   const float* __restrict__ b2,
                                                   float* __restrict__ out) {
    int b = blockIdx.y;
    int px = blockIdx.x * 256 + threadIdx.x;
    int y = px >> 7, x = px & 127;

    float m[9];
    int off[9];
#pragma unroll
    for (int dy = -1; dy <= 1; ++dy)
#pragma unroll
        for (int dx = -1; dx <= 1; ++dx) {
            int i = (dy + 1) * 3 + (dx + 1);
            int yy = y + dy, xx = x + dx;
            bool valid = (yy >= 0 && yy < HH && xx >= 0 && xx < WW);
            m[i] = valid ? 1.f : 0.f;
            int yc = min(max(yy, 0), HH - 1), xc = min(max(xx, 0), WW - 1);
            off[i] = yc * WW + xc;
        }

    float acc[KK];
#pragma unroll
    for (int ko = 0; ko < KK; ++ko) acc[ko] = b2[ko];
#pragma unroll
    for (int i = 0; i < 9; ++i)
#pragma unroll
        for (int ko = 0; ko < KK; ++ko) acc[ko] += m[i] * bcon[ko * 9 + i];

    const float* a2b = attn2 + (size_t)b * KK * HWHW;
    const float* wab = w2a + (size_t)b * KK * KK * 9;
    float tap[2][9];
#pragma unroll
    for (int i = 0; i < 9; ++i) tap[0][i] = m[i] * a2b[off[i]];  // k=0
#pragma unroll 2
    for (int k = 0; k < KK; ++k) {
        if (k < KK - 1) {
#pragma unroll
            for (int i = 0; i < 9; ++i)
                tap[(k + 1) & 1][i] = m[i] * a2b[(size_t)(k + 1) * HWHW + off[i]];
        }
#pragma unroll
        for (int ko = 0; ko < KK; ++ko)
#pragma unroll
            for (int i = 0; i < 9; ++i)
                acc[ko] += wab[(ko * KK + k) * 9 + i] * tap[k & 1][i];
    }

    size_t obase = ((size_t)b * KK) * HWHW + (size_t)y * WW + x;
#pragma unroll
    for (int ko = 0; ko < KK; ++ko) out[obase + (size_t)ko * HWHW] = acc[ko];
}

// ---------------- out += conv3x3(feature, w2_right); LDS tap staging ----------------
#define NSOUT 8
#define SUBC 8
__global__ __launch_bounds__(256) void out_kernel(const h2* __restrict__ fpk,
                                                  const h2* __restrict__ wpk,
                                                  float* __restrict__ out) {
    __shared__ h2 st[SUBC * 4 * 130];  // 16640 B
    int b = blockIdx.y, ns = blockIdx.z;
    int t = threadIdx.x;
    int w = t >> 7;   // output row within block (0/1)
    int x = t & 127;
    int y0 = blockIdx.x * 2;

    h2 hz; hz[0] = (_Float16)0.f; hz[1] = (_Float16)0.f;

    // zero the two halo columns once (stage loop never writes x-index 0 or 129)
    if (t < SUBC * 4 * 2) {
        int c2r = t >> 1;
        int side = t & 1;
        st[c2r * 130 + side * 129] = hz;
    }

    int cb = ns * (C2 / NSOUT);  // 32 c2 per block
    const h2* fbase = fpk + ((size_t)b * C2 + cb) * HWHW;

    float acc[KK];
#pragma unroll
    for (int ko = 0; ko < KK; ++ko) acc[ko] = 0.f;

    for (int ch = 0; ch < (C2 / NSOUT) / SUBC; ++ch) {  // 4 chunks
        __syncthreads();  // prev compute done (also covers halo init on ch=0)
#pragma unroll
        for (int e = 0; e < (SUBC * 4 * 128) / 256; ++e) {  // 16 staging loads
            int idx = e * 256 + t;
            int c2s = idx >> 9;
            int rem = idx & 511;
            int r = rem >> 7;
            int xx = rem & 127;
            int yy = y0 - 1 + r;
            h2 v = hz;
            if (yy >= 0 && yy < HH)
                v = fbase[(size_t)(ch * SUBC + c2s) * HWHW + yy * WW + xx];
            st[(c2s * 4 + r) * 130 + xx + 1] = v;
        }
        __syncthreads();
        for (int c2s = 0; c2s < SUBC; ++c2s) {
            h2 tp[9];
#pragma unroll
            for (int dy = 0; dy < 3; ++dy)
#pragma unroll
                for (int dx = 0; dx < 3; ++dx)
                    tp[dy * 3 + dx] = st[(c2s * 4 + w + dy) * 130 + x + dx];
            const h2* wr = wpk + (size_t)(cb + ch * SUBC + c2s) * 171;  // uniform -> s_load
#pragma unroll
            for (int j = 0; j < 171; ++j)
                acc[j / 9] = __builtin_amdgcn_fdot2(wr[j], tp[j % 9], acc[j / 9], false);
        }
    }

    size_t obase = ((size_t)b * KK) * HWHW + (size_t)(y0 + w) * WW + x;
#pragma unroll
    for (int ko = 0; ko < KK; ++ko) atomicAdd(&out[obase + (size_t)ko * HWHW], acc[ko]);
}

extern "C" void kernel_launch(void* const* d_in, const int* in_sizes, int n_in,
                              void* d_out, int out_size, void* d_ws, size_t ws_size,
                              hipStream_t stream) {
    const float* ctx = (const float*)d_in[0];
    const float* feature = (const float*)d_in[1];
    const float* w1 = (const float*)d_in[2];
    const float* b1 = (const float*)d_in[3];
    const float* w2 = (const float*)d_in[4];
    const float* b2 = (const float*)d_in[5];
    float* out = (float*)d_out;

    // workspace layout
    float* ws = (float*)d_ws;
    float* attn = ws;                              // B*K*HW (reused as rel/attn2)
    float* ocr = attn + (size_t)BB * KK * HWHW;    // 38,912
    float* ocr2 = ocr + (size_t)BB * CC * KK;      // 38,912
    float* w2a = ocr2 + (size_t)BB * CC * KK;      // 12,996
    float* bcon = w2a + (size_t)BB * KK * KK * 9;  // 171
    h2* fpk = (h2*)(bcon + KK * 9 + 1);            // B*C2*HW h2 = 67.1 MB
    h2* opk = fpk + (size_t)BB * C2 * HWHW;        // B*C2*K
    h2* wpk = opk + (size_t)BB * C2 * KK;          // C2*171

    hipMemsetAsync(ocr, 0, (size_t)BB * CC * KK * sizeof(float), stream);

    softmax_rows<<<BB * KK, 1024, 0, stream>>>(ctx, attn);
    ocr_kernel<<<dim3(CC / 16, BB, NSPLIT), 256, 0, stream>>>(feature, attn, ocr, fpk);
    ocr2_kernel<<<dim3(CC, BB), 64, 0, stream>>>(w1, ocr, ocr2);
    wpk_kernel<<<(C2 * 171 + 255) / 256, 256, 0, stream>>>(w2, wpk);
    w2a_kernel<<<dim3(KK, 9, BB), 64, 0, stream>>>(w2, ocr2, b1, w2a, bcon);
    opk_kernel<<<BB, 256, 0, stream>>>(ocr, opk);
    // reuse attn buffer for rel accumulation
    hipMemsetAsync(attn, 0, (size_t)BB * KK * HWHW * sizeof(float), stream);
    rel_kernel<<<dim3(HWHW / 256, BB, NSREL), 256, 0, stream>>>(fpk, opk, attn);
    softmax_rows<<<BB * KK, 1024, 0, stream>>>(attn, attn);  // attn2 in place
    // outa writes out fully (bias + bcon + rank-19 conv), then out_kernel atomically adds
    outa_kernel<<<dim3(HWHW / 256, BB), 256, 0, stream>>>(attn, w2a, bcon, b2, out);
    out_kernel<<<dim3(HH / 2, BB, NSOUT), 256, 0, stream>>>(fpk, wpk, out);
}